// Round 1
// baseline (2624.802 us; speedup 1.0000x reference)
//
#include <hip/hip_runtime.h>
#include <math.h>

#define NR 10
#define CH 7
#define HID 128
#define NH 4
#define NL 3
#define TOK_FEATS (NR * HID)          // 1280
#define B_TIMES_T 16384

__device__ __forceinline__ float gelu_exact(float x) {
    return 0.5f * x * (1.0f + erff(x * 0.70710678118654752f));
}

// adjacency bitmasks: bit j of kAdj[i] == adj[i][j] (incl self loops)
__device__ __constant__ unsigned short kAdj[NR] = {
    0x01F, 0x0A7, 0x08F, 0x00D, 0x031, 0x072, 0x260, 0x186, 0x180, 0x240
};

__global__ void __launch_bounds__(256)
brain_graph_kernel(const float* __restrict__ x,
                   const float* __restrict__ W_enc,
                   const float* __restrict__ b_enc,
                   const float* __restrict__ g_enc,
                   const float* __restrict__ beta_enc,
                   const float* __restrict__ W_gat,
                   const float* __restrict__ att_src,
                   const float* __restrict__ att_dst,
                   const float* __restrict__ b_gat,
                   float* __restrict__ out_gf,
                   float* __restrict__ out_enc) {
    const int token = blockIdx.x;
    const int tid = threadIdx.x;

    __shared__ float s_x[NR * CH];            // 70
    __shared__ float s_nodes[NR * HID];       // 1280
    __shared__ float s_hh[NR * NH * HID];     // 5120
    __shared__ float s_as[NR * NH];           // 40
    __shared__ float s_ad[NR * NH];           // 40
    __shared__ float s_alpha[NR * NH * NR];   // 400

    // ---------------- encoder: Linear(7->128) ----------------
    if (tid < NR * CH) s_x[tid] = x[token * (NR * CH) + tid];
    __syncthreads();

    #pragma unroll
    for (int k = 0; k < 5; ++k) {
        const int flat = tid + k * 256;       // r*128 + d
        const int r = flat >> 7;
        const int d = flat & 127;
        float acc = b_enc[flat];
        const float* wp = W_enc + (r * CH) * HID + d;
        const float* xp = s_x + r * CH;
        #pragma unroll
        for (int c = 0; c < CH; ++c) acc = fmaf(xp[c], wp[c * HID], acc);
        s_nodes[flat] = acc;
    }
    __syncthreads();

    // ---------------- encoder: LayerNorm + GELU ----------------
    {
        const int wave = tid >> 6;
        const int lane = tid & 63;
        for (int r = wave; r < NR; r += 4) {
            const float v0 = s_nodes[r * HID + lane];
            const float v1 = s_nodes[r * HID + lane + 64];
            float s = v0 + v1;
            float sq = v0 * v0 + v1 * v1;
            #pragma unroll
            for (int off = 32; off > 0; off >>= 1) {
                s += __shfl_xor(s, off);
                sq += __shfl_xor(sq, off);
            }
            const float mu = s * (1.0f / 128.0f);
            const float var = sq * (1.0f / 128.0f) - mu * mu;
            const float rstd = rsqrtf(var + 1e-5f);
            const float e0 = gelu_exact((v0 - mu) * rstd * g_enc[r * HID + lane] + beta_enc[r * HID + lane]);
            const float e1 = gelu_exact((v1 - mu) * rstd * g_enc[r * HID + lane + 64] + beta_enc[r * HID + lane + 64]);
            s_nodes[r * HID + lane] = e0;
            s_nodes[r * HID + lane + 64] = e1;
            out_enc[(size_t)token * TOK_FEATS + r * HID + lane] = e0;
            out_enc[(size_t)token * TOK_FEATS + r * HID + lane + 64] = e1;
        }
    }

    // ---------------- GAT layers ----------------
    for (int l = 0; l < NL; ++l) {
        const float* Wl  = W_gat + l * (HID * NH * HID);   // [d][h*128+e], row stride 512
        const float* asp = att_src + l * (NH * HID);
        const float* adp = att_dst + l * (NH * HID);
        const float* bgp = b_gat + l * HID;

        __syncthreads();   // nodes ready; previous layer done with s_hh

        // phase 1: hh[n][col] for col = tid, tid+256
        {
            float acc0[NR], acc1[NR];
            #pragma unroll
            for (int n = 0; n < NR; ++n) { acc0[n] = 0.f; acc1[n] = 0.f; }
            const float4* nodes4 = (const float4*)s_nodes;
            for (int d4 = 0; d4 < 32; ++d4) {
                float4 nv[NR];
                #pragma unroll
                for (int n = 0; n < NR; ++n) nv[n] = nodes4[n * 32 + d4];
                #pragma unroll
                for (int q = 0; q < 4; ++q) {
                    const int d = d4 * 4 + q;
                    const float w0 = Wl[d * 512 + tid];
                    const float w1 = Wl[d * 512 + tid + 256];
                    #pragma unroll
                    for (int n = 0; n < NR; ++n) {
                        const float nd = (q == 0) ? nv[n].x : (q == 1) ? nv[n].y : (q == 2) ? nv[n].z : nv[n].w;
                        acc0[n] = fmaf(nd, w0, acc0[n]);
                        acc1[n] = fmaf(nd, w1, acc1[n]);
                    }
                }
            }
            #pragma unroll
            for (int n = 0; n < NR; ++n) {
                s_hh[n * 512 + tid] = acc0[n];
                s_hh[n * 512 + tid + 256] = acc1[n];
            }
        }
        __syncthreads();

        // phase 2: a_src / a_dst (threads 0..159: n = tid/16, h = (tid/4)%4, part = tid%4)
        if (tid < NR * NH * 4) {
            const int n = tid >> 4;
            const int h = (tid >> 2) & 3;
            const int part = tid & 3;
            float vs = 0.f, vd = 0.f;
            const float* hp = s_hh + n * 512 + h * 128 + part * 32;
            const float* ap = asp + h * 128 + part * 32;
            const float* dp = adp + h * 128 + part * 32;
            const int rot = tid & 31;
            #pragma unroll
            for (int ee = 0; ee < 32; ++ee) {
                const int e = (ee + rot) & 31;   // rotate to avoid same-bank LDS access
                const float hv = hp[e];
                vs = fmaf(hv, ap[e], vs);
                vd = fmaf(hv, dp[e], vd);
            }
            vs += __shfl_xor(vs, 1); vs += __shfl_xor(vs, 2);
            vd += __shfl_xor(vd, 1); vd += __shfl_xor(vd, 2);
            if (part == 0) {
                s_as[n * NH + h] = vs;
                s_ad[n * NH + h] = vd;
            }
        }
        __syncthreads();

        // phase 3: leaky-relu + mask + softmax over sources j (threads 0..39: i = tid/4, h = tid%4)
        if (tid < NR * NH) {
            const int i = tid >> 2;
            const int h = tid & 3;
            const unsigned mask = kAdj[i];
            const float adv = s_ad[i * NH + h];
            float lg[NR];
            float mx = -1e30f;
            #pragma unroll
            for (int j = 0; j < NR; ++j) {
                float v = adv + s_as[j * NH + h];
                v = (v > 0.f) ? v : 0.2f * v;
                v = ((mask >> j) & 1u) ? v : -1e9f;
                lg[j] = v;
                mx = fmaxf(mx, v);
            }
            float ssum = 0.f;
            #pragma unroll
            for (int j = 0; j < NR; ++j) {
                const float e = expf(lg[j] - mx);
                lg[j] = e;
                ssum += e;
            }
            const float inv = 1.0f / ssum;
            #pragma unroll
            for (int j = 0; j < NR; ++j) s_alpha[tid * NR + j] = lg[j] * inv;
        }
        __syncthreads();

        // phase 4: aggregate, mean over heads, bias, GELU, residual
        #pragma unroll
        for (int k = 0; k < 5; ++k) {
            const int flat = tid + k * 256;   // i*128 + e
            const int i = flat >> 7;
            const int e = flat & 127;
            float acc = 0.f;
            #pragma unroll
            for (int h = 0; h < NH; ++h) {
                const float* al = s_alpha + (i * NH + h) * NR;
                const float* hp = s_hh + h * 128 + e;
                #pragma unroll
                for (int j = 0; j < NR; ++j) acc = fmaf(al[j], hp[j * 512], acc);
            }
            const float outv = acc * 0.25f + bgp[e];
            const float nv = gelu_exact(outv) + s_nodes[flat];
            if (l == NL - 1) out_gf[(size_t)token * TOK_FEATS + flat] = nv;
            else s_nodes[flat] = nv;
        }
    }
}

extern "C" void kernel_launch(void* const* d_in, const int* in_sizes, int n_in,
                              void* d_out, int out_size, void* d_ws, size_t ws_size,
                              hipStream_t stream) {
    const float* x        = (const float*)d_in[0];
    const float* W_enc    = (const float*)d_in[1];
    const float* b_enc    = (const float*)d_in[2];
    const float* g_enc    = (const float*)d_in[3];
    const float* beta_enc = (const float*)d_in[4];
    const float* W_gat    = (const float*)d_in[5];
    const float* att_src  = (const float*)d_in[6];
    const float* att_dst  = (const float*)d_in[7];
    const float* b_gat    = (const float*)d_in[8];

    float* out_gf  = (float*)d_out;
    float* out_enc = (float*)d_out + (size_t)B_TIMES_T * TOK_FEATS;

    brain_graph_kernel<<<B_TIMES_T, 256, 0, stream>>>(
        x, W_enc, b_enc, g_enc, beta_enc, W_gat, att_src, att_dst, b_gat,
        out_gf, out_enc);
}

// Round 2
// 1524.357 us; speedup vs baseline: 1.7219x; 1.7219x over previous
//
#include <hip/hip_runtime.h>
#include <math.h>

#define NR 10
#define CH 7
#define HID 128
#define NH 4
#define NL 3
#define TOK_FEATS (NR * HID)   // 1280
#define NTOK 16384

__device__ __forceinline__ float gelu_exact(float x) {
    return 0.5f * x * (1.0f + erff(x * 0.70710678118654752f));
}

// wave-uniform broadcast via readlane (VALU/scalar, keeps the LDS pipe free)
__device__ __forceinline__ float rlane(float v, int lane) {
    return __int_as_float(__builtin_amdgcn_readlane(__float_as_int(v), lane));
}

// adjacency bitmasks: bit j of kAdj[i] == adj[i][j] (incl self loops)
__device__ __constant__ unsigned short kAdj[NR] = {
    0x01F, 0x0A7, 0x08F, 0x00D, 0x031, 0x072, 0x260, 0x186, 0x180, 0x240
};

__global__ void __launch_bounds__(256, 3)
brain_graph_kernel(const float* __restrict__ x,
                   const float* __restrict__ W_enc,
                   const float* __restrict__ b_enc,
                   const float* __restrict__ g_enc,
                   const float* __restrict__ beta_enc,
                   const float* __restrict__ W_gat,
                   const float* __restrict__ att_src,
                   const float* __restrict__ att_dst,
                   const float* __restrict__ b_gat,
                   float* __restrict__ out_gf,
                   float* __restrict__ out_enc) {
    const int wave = threadIdx.x >> 6;
    const int lane = threadIdx.x & 63;
    const int token = blockIdx.x * 4 + wave;   // one wave <-> one token, no barriers

    __shared__ float s_nodes_all[4][TOK_FEATS];     // 20480 B
    __shared__ float s_asd_all[4][NR * 8];          // 1280 B  [n][src/dst][h]
    __shared__ float s_alpha_all[4][NR * NR * 4];   // 6400 B  [(i*10+j)*4 + h]
    float* s_nodes = s_nodes_all[wave];
    float* s_asd   = s_asd_all[wave];
    float* s_alpha = s_alpha_all[wave];

    // ================= encoder: Linear(7->128) + LN + GELU =================
    // x for this token lives distributed in 2 regs/lane; broadcast by readlane
    const float xv0 = x[(size_t)token * (NR * CH) + lane];
    const float xv1 = (lane < NR * CH - 64) ? x[(size_t)token * (NR * CH) + 64 + lane] : 0.f;
    {
        const int d0 = lane, d1 = lane + 64;
        #pragma unroll
        for (int r = 0; r < NR; ++r) {
            float a0 = b_enc[r * HID + d0];
            float a1 = b_enc[r * HID + d1];
            #pragma unroll
            for (int c = 0; c < CH; ++c) {
                const int idx = r * CH + c;
                const float xs = (idx < 64) ? rlane(xv0, idx) : rlane(xv1, idx - 64);
                a0 = fmaf(xs, W_enc[idx * HID + d0], a0);
                a1 = fmaf(xs, W_enc[idx * HID + d1], a1);
            }
            float s = a0 + a1, sq = a0 * a0 + a1 * a1;
            #pragma unroll
            for (int off = 32; off > 0; off >>= 1) {
                s += __shfl_xor(s, off);
                sq += __shfl_xor(sq, off);
            }
            const float mu = s * (1.0f / 128.0f);
            const float rstd = rsqrtf(sq * (1.0f / 128.0f) - mu * mu + 1e-5f);
            const float e0 = gelu_exact((a0 - mu) * rstd * g_enc[r * HID + d0] + beta_enc[r * HID + d0]);
            const float e1 = gelu_exact((a1 - mu) * rstd * g_enc[r * HID + d1] + beta_enc[r * HID + d1]);
            s_nodes[r * HID + d0] = e0;
            s_nodes[r * HID + d1] = e1;
            out_enc[(size_t)token * TOK_FEATS + r * HID + d0] = e0;
            out_enc[(size_t)token * TOK_FEATS + r * HID + d1] = e1;
        }
    }

    const int hl = lane >> 4;          // head owning this lane's 8 cols
    const int e8 = (lane & 15) * 8;    // e-range base within the head

    // ================= GAT layers =================
    for (int l = 0; l < NL; ++l) {
        // nodes -> distributed regs (readlane source)
        float nd0[NR], nd1[NR];
        #pragma unroll
        for (int n = 0; n < NR; ++n) {
            nd0[n] = s_nodes[n * HID + lane];
            nd1[n] = s_nodes[n * HID + 64 + lane];
        }

        // phase 1: hh[n][c] for cols c = 8*lane .. 8*lane+7, all 10 n, in regs
        float acc[NR][8];
        #pragma unroll
        for (int n = 0; n < NR; ++n)
            #pragma unroll
            for (int k = 0; k < 8; ++k) acc[n][k] = 0.f;

        const float* wp = W_gat + (size_t)l * HID * 512 + lane * 8;
        #pragma unroll
        for (int half = 0; half < 2; ++half) {
            #pragma unroll 4
            for (int dd = 0; dd < 64; ++dd) {
                const float4 w0 = *(const float4*)(wp);
                const float4 w1 = *(const float4*)(wp + 4);
                wp += 512;
                const float wv[8] = {w0.x, w0.y, w0.z, w0.w, w1.x, w1.y, w1.z, w1.w};
                #pragma unroll
                for (int n = 0; n < NR; ++n) {
                    const float sv = rlane(half ? nd1[n] : nd0[n], dd);
                    #pragma unroll
                    for (int k = 0; k < 8; ++k) acc[n][k] = fmaf(sv, wv[k], acc[n][k]);
                }
            }
        }

        // phase 2: a_src/a_dst via per-lane partials + 16-lane butterfly
        {
            const float* ap = att_src + l * (NH * HID) + hl * HID + e8;
            const float* dp = att_dst + l * (NH * HID) + hl * HID + e8;
            const float4 A0 = *(const float4*)ap, A1 = *(const float4*)(ap + 4);
            const float4 D0 = *(const float4*)dp, D1 = *(const float4*)(dp + 4);
            const float as_[8] = {A0.x, A0.y, A0.z, A0.w, A1.x, A1.y, A1.z, A1.w};
            const float ad_[8] = {D0.x, D0.y, D0.z, D0.w, D1.x, D1.y, D1.z, D1.w};
            #pragma unroll
            for (int n = 0; n < NR; ++n) {
                float ps = 0.f, pd = 0.f;
                #pragma unroll
                for (int k = 0; k < 8; ++k) {
                    ps = fmaf(acc[n][k], as_[k], ps);
                    pd = fmaf(acc[n][k], ad_[k], pd);
                }
                #pragma unroll
                for (int off = 1; off < 16; off <<= 1) {
                    ps += __shfl_xor(ps, off);
                    pd += __shfl_xor(pd, off);
                }
                if ((lane & 15) == 0) {
                    s_asd[n * 8 + hl] = ps;
                    s_asd[n * 8 + 4 + hl] = pd;
                }
            }
        }

        // phase 3: masked leaky-relu softmax over sources (lanes 0..39)
        if (lane < NR * NH) {
            const int i = lane >> 2, h = lane & 3;
            const unsigned mask = kAdj[i];
            const float adv = s_asd[i * 8 + 4 + h];
            float lg[NR];
            float mx = -1e30f;
            #pragma unroll
            for (int j = 0; j < NR; ++j) {
                float v = adv + s_asd[j * 8 + h];
                v = (v > 0.f) ? v : 0.2f * v;
                v = ((mask >> j) & 1u) ? v : -1e9f;
                lg[j] = v;
                mx = fmaxf(mx, v);
            }
            float ssum = 0.f;
            #pragma unroll
            for (int j = 0; j < NR; ++j) {
                const float e = __expf(lg[j] - mx);
                lg[j] = e;
                ssum += e;
            }
            const float inv = 1.0f / ssum;
            #pragma unroll
            for (int j = 0; j < NR; ++j) s_alpha[(i * NR + j) * 4 + h] = lg[j] * inv;
        }

        // phase 4: per-head partial aggregate in regs, butterfly over heads,
        // mean + bias + GELU + residual
        const float* bg = b_gat + l * HID;
        #pragma unroll
        for (int i = 0; i < NR; ++i) {
            float o[8];
            #pragma unroll
            for (int k = 0; k < 8; ++k) o[k] = 0.f;
            #pragma unroll
            for (int j = 0; j < NR; ++j) {
                const float a = s_alpha[(i * NR + j) * 4 + hl];
                #pragma unroll
                for (int k = 0; k < 8; ++k) o[k] = fmaf(a, acc[j][k], o[k]);
            }
            #pragma unroll
            for (int k = 0; k < 8; ++k) {
                o[k] += __shfl_xor(o[k], 16);
                o[k] += __shfl_xor(o[k], 32);
            }
            #pragma unroll
            for (int k = 0; k < 8; ++k) {
                o[k] = gelu_exact(o[k] * 0.25f + bg[e8 + k]) + s_nodes[i * HID + e8 + k];
            }
            if (lane < 16) {
                #pragma unroll
                for (int k = 0; k < 8; ++k) s_nodes[i * HID + e8 + k] = o[k];
                if (l == NL - 1) {
                    #pragma unroll
                    for (int k = 0; k < 8; ++k)
                        out_gf[(size_t)token * TOK_FEATS + i * HID + e8 + k] = o[k];
                }
            }
        }
    }
}

extern "C" void kernel_launch(void* const* d_in, const int* in_sizes, int n_in,
                              void* d_out, int out_size, void* d_ws, size_t ws_size,
                              hipStream_t stream) {
    const float* x        = (const float*)d_in[0];
    const float* W_enc    = (const float*)d_in[1];
    const float* b_enc    = (const float*)d_in[2];
    const float* g_enc    = (const float*)d_in[3];
    const float* beta_enc = (const float*)d_in[4];
    const float* W_gat    = (const float*)d_in[5];
    const float* att_src  = (const float*)d_in[6];
    const float* att_dst  = (const float*)d_in[7];
    const float* b_gat    = (const float*)d_in[8];

    float* out_gf  = (float*)d_out;
    float* out_enc = (float*)d_out + (size_t)NTOK * TOK_FEATS;

    brain_graph_kernel<<<NTOK / 4, 256, 0, stream>>>(
        x, W_enc, b_enc, g_enc, beta_enc, W_gat, att_src, att_dst, b_gat,
        out_gf, out_enc);
}

// Round 3
// 1432.002 us; speedup vs baseline: 1.8330x; 1.0645x over previous
//
#include <hip/hip_runtime.h>
#include <math.h>

#define NR 10
#define CH 7
#define HID 128
#define NH 4
#define NL 3
#define TOK_FEATS (NR * HID)   // 1280
#define NTOK 16384

__device__ __forceinline__ float gelu_exact(float x) {
    return 0.5f * x * (1.0f + erff(x * 0.70710678118654752f));
}

// wave-uniform broadcast via readlane (VALU/scalar, keeps the LDS pipe free)
__device__ __forceinline__ float rlane(float v, int lane) {
    return __int_as_float(__builtin_amdgcn_readlane(__float_as_int(v), lane));
}

// adjacency bitmasks: bit j of kAdj[i] == adj[i][j] (incl self loops)
__device__ __constant__ unsigned short kAdj[NR] = {
    0x01F, 0x0A7, 0x08F, 0x00D, 0x031, 0x072, 0x260, 0x186, 0x180, 0x240
};

// __launch_bounds__(256,4): VGPR cap = 128 exactly (occupancy tier boundary,
// 4 waves/SIMD). (256,3) made the allocator spill acc[10][8] to scratch
// (VGPR_Count=84, +150MB HBM scratch traffic in R2).
__global__ void __launch_bounds__(256, 4)
brain_graph_kernel(const float* __restrict__ x,
                   const float* __restrict__ W_enc,
                   const float* __restrict__ b_enc,
                   const float* __restrict__ g_enc,
                   const float* __restrict__ beta_enc,
                   const float* __restrict__ W_gat,
                   const float* __restrict__ att_src,
                   const float* __restrict__ att_dst,
                   const float* __restrict__ b_gat,
                   float* __restrict__ out_gf,
                   float* __restrict__ out_enc) {
    const int wave = threadIdx.x >> 6;
    const int lane = threadIdx.x & 63;
    const int token = blockIdx.x * 4 + wave;   // one wave <-> one token, no barriers

    __shared__ float s_nodes_all[4][TOK_FEATS];     // 20480 B
    __shared__ float s_asd_all[4][NR * 8];          // 1280 B  [n][src/dst][h]
    __shared__ float s_alpha_all[4][NR * NR * 4];   // 6400 B  [(i*10+j)*4 + h]
    float* s_nodes = s_nodes_all[wave];
    float* s_asd   = s_asd_all[wave];
    float* s_alpha = s_alpha_all[wave];

    // ================= encoder: Linear(7->128) + LN + GELU =================
    const float xv0 = x[(size_t)token * (NR * CH) + lane];
    const float xv1 = (lane < NR * CH - 64) ? x[(size_t)token * (NR * CH) + 64 + lane] : 0.f;
    {
        const int d0 = lane, d1 = lane + 64;
        #pragma unroll
        for (int r = 0; r < NR; ++r) {
            float a0 = b_enc[r * HID + d0];
            float a1 = b_enc[r * HID + d1];
            #pragma unroll
            for (int c = 0; c < CH; ++c) {
                const int idx = r * CH + c;
                const float xs = (idx < 64) ? rlane(xv0, idx) : rlane(xv1, idx - 64);
                a0 = fmaf(xs, W_enc[idx * HID + d0], a0);
                a1 = fmaf(xs, W_enc[idx * HID + d1], a1);
            }
            float s = a0 + a1, sq = a0 * a0 + a1 * a1;
            #pragma unroll
            for (int off = 32; off > 0; off >>= 1) {
                s += __shfl_xor(s, off);
                sq += __shfl_xor(sq, off);
            }
            const float mu = s * (1.0f / 128.0f);
            const float rstd = rsqrtf(sq * (1.0f / 128.0f) - mu * mu + 1e-5f);
            const float e0 = gelu_exact((a0 - mu) * rstd * g_enc[r * HID + d0] + beta_enc[r * HID + d0]);
            const float e1 = gelu_exact((a1 - mu) * rstd * g_enc[r * HID + d1] + beta_enc[r * HID + d1]);
            s_nodes[r * HID + d0] = e0;
            s_nodes[r * HID + d1] = e1;
            out_enc[(size_t)token * TOK_FEATS + r * HID + d0] = e0;
            out_enc[(size_t)token * TOK_FEATS + r * HID + d1] = e1;
        }
    }

    const int hl = lane >> 4;          // head owning this lane's 8 cols
    const int e8 = (lane & 15) * 8;    // e-range base within the head

    // ================= GAT layers =================
    for (int l = 0; l < NL; ++l) {
        // nodes -> distributed regs (readlane source)
        float nd0[NR], nd1[NR];
        #pragma unroll
        for (int n = 0; n < NR; ++n) {
            nd0[n] = s_nodes[n * HID + lane];
            nd1[n] = s_nodes[n * HID + 64 + lane];
        }

        // phase 1: hh[n][c] for cols c = 8*lane .. 8*lane+7, all 10 n, in regs
        float acc[NR][8];
        #pragma unroll
        for (int n = 0; n < NR; ++n)
            #pragma unroll
            for (int k = 0; k < 8; ++k) acc[n][k] = 0.f;

        const float* wp = W_gat + (size_t)l * HID * 512 + lane * 8;
        #pragma unroll
        for (int half = 0; half < 2; ++half) {
            #pragma unroll 2
            for (int dd = 0; dd < 64; ++dd) {
                const float4 w0 = *(const float4*)(wp);
                const float4 w1 = *(const float4*)(wp + 4);
                wp += 512;
                #pragma unroll
                for (int n = 0; n < NR; ++n) {
                    const float sv = rlane(half ? nd1[n] : nd0[n], dd);
                    acc[n][0] = fmaf(sv, w0.x, acc[n][0]);
                    acc[n][1] = fmaf(sv, w0.y, acc[n][1]);
                    acc[n][2] = fmaf(sv, w0.z, acc[n][2]);
                    acc[n][3] = fmaf(sv, w0.w, acc[n][3]);
                    acc[n][4] = fmaf(sv, w1.x, acc[n][4]);
                    acc[n][5] = fmaf(sv, w1.y, acc[n][5]);
                    acc[n][6] = fmaf(sv, w1.z, acc[n][6]);
                    acc[n][7] = fmaf(sv, w1.w, acc[n][7]);
                }
            }
        }

        // phase 2: a_src/a_dst via per-lane partials + 16-lane butterfly
        {
            const float* ap = att_src + l * (NH * HID) + hl * HID + e8;
            const float* dp = att_dst + l * (NH * HID) + hl * HID + e8;
            const float4 A0 = *(const float4*)ap, A1 = *(const float4*)(ap + 4);
            const float4 D0 = *(const float4*)dp, D1 = *(const float4*)(dp + 4);
            #pragma unroll
            for (int n = 0; n < NR; ++n) {
                float ps = 0.f, pd = 0.f;
                ps = fmaf(acc[n][0], A0.x, ps); pd = fmaf(acc[n][0], D0.x, pd);
                ps = fmaf(acc[n][1], A0.y, ps); pd = fmaf(acc[n][1], D0.y, pd);
                ps = fmaf(acc[n][2], A0.z, ps); pd = fmaf(acc[n][2], D0.z, pd);
                ps = fmaf(acc[n][3], A0.w, ps); pd = fmaf(acc[n][3], D0.w, pd);
                ps = fmaf(acc[n][4], A1.x, ps); pd = fmaf(acc[n][4], D1.x, pd);
                ps = fmaf(acc[n][5], A1.y, ps); pd = fmaf(acc[n][5], D1.y, pd);
                ps = fmaf(acc[n][6], A1.z, ps); pd = fmaf(acc[n][6], D1.z, pd);
                ps = fmaf(acc[n][7], A1.w, ps); pd = fmaf(acc[n][7], D1.w, pd);
                #pragma unroll
                for (int off = 1; off < 16; off <<= 1) {
                    ps += __shfl_xor(ps, off);
                    pd += __shfl_xor(pd, off);
                }
                if ((lane & 15) == 0) {
                    s_asd[n * 8 + hl] = ps;
                    s_asd[n * 8 + 4 + hl] = pd;
                }
            }
        }

        // phase 3: masked leaky-relu softmax over sources (lanes 0..39)
        if (lane < NR * NH) {
            const int i = lane >> 2, h = lane & 3;
            const unsigned mask = kAdj[i];
            const float adv = s_asd[i * 8 + 4 + h];
            float lg[NR];
            float mx = -1e30f;
            #pragma unroll
            for (int j = 0; j < NR; ++j) {
                float v = adv + s_asd[j * 8 + h];
                v = (v > 0.f) ? v : 0.2f * v;
                v = ((mask >> j) & 1u) ? v : -1e9f;
                lg[j] = v;
                mx = fmaxf(mx, v);
            }
            float ssum = 0.f;
            #pragma unroll
            for (int j = 0; j < NR; ++j) {
                const float e = __expf(lg[j] - mx);
                lg[j] = e;
                ssum += e;
            }
            const float inv = 1.0f / ssum;
            #pragma unroll
            for (int j = 0; j < NR; ++j) s_alpha[(i * NR + j) * 4 + h] = lg[j] * inv;
        }

        // phase 4: per-head partial aggregate in regs, butterfly over heads,
        // mean + bias + GELU + residual
        const float* bg = b_gat + l * HID;
        #pragma unroll
        for (int i = 0; i < NR; ++i) {
            float o[8];
            #pragma unroll
            for (int k = 0; k < 8; ++k) o[k] = 0.f;
            #pragma unroll
            for (int j = 0; j < NR; ++j) {
                const float a = s_alpha[(i * NR + j) * 4 + hl];
                #pragma unroll
                for (int k = 0; k < 8; ++k) o[k] = fmaf(a, acc[j][k], o[k]);
            }
            #pragma unroll
            for (int k = 0; k < 8; ++k) {
                o[k] += __shfl_xor(o[k], 16);
                o[k] += __shfl_xor(o[k], 32);
            }
            #pragma unroll
            for (int k = 0; k < 8; ++k) {
                o[k] = gelu_exact(o[k] * 0.25f + bg[e8 + k]) + s_nodes[i * HID + e8 + k];
            }
            if (lane < 16) {
                #pragma unroll
                for (int k = 0; k < 8; ++k) s_nodes[i * HID + e8 + k] = o[k];
                if (l == NL - 1) {
                    #pragma unroll
                    for (int k = 0; k < 8; ++k)
                        out_gf[(size_t)token * TOK_FEATS + i * HID + e8 + k] = o[k];
                }
            }
        }
    }
}

extern "C" void kernel_launch(void* const* d_in, const int* in_sizes, int n_in,
                              void* d_out, int out_size, void* d_ws, size_t ws_size,
                              hipStream_t stream) {
    const float* x        = (const float*)d_in[0];
    const float* W_enc    = (const float*)d_in[1];
    const float* b_enc    = (const float*)d_in[2];
    const float* g_enc    = (const float*)d_in[3];
    const float* beta_enc = (const float*)d_in[4];
    const float* W_gat    = (const float*)d_in[5];
    const float* att_src  = (const float*)d_in[6];
    const float* att_dst  = (const float*)d_in[7];
    const float* b_gat    = (const float*)d_in[8];

    float* out_gf  = (float*)d_out;
    float* out_enc = (float*)d_out + (size_t)NTOK * TOK_FEATS;

    brain_graph_kernel<<<NTOK / 4, 256, 0, stream>>>(
        x, W_enc, b_enc, g_enc, beta_enc, W_gat, att_src, att_dst, b_gat,
        out_gf, out_enc);
}